// Round 11
// baseline (860.256 us; speedup 1.0000x reference)
//
#include <hip/hip_runtime.h>
#include <hip/hip_bf16.h>

#define VOCAB 32000
#define HIDDEN 1024
#define BATCH 32
#define SEQ 128

typedef short bf8v __attribute__((ext_vector_type(8)));   // 8 x bf16 payload
typedef float f32x4 __attribute__((ext_vector_type(4)));
typedef unsigned long long u64;
typedef unsigned int u32;

static __device__ __forceinline__ short f2bf(float f) {
    return __builtin_bit_cast(short, __float2bfloat16(f));
}
static __device__ __forceinline__ float bf2f(short s) {
    unsigned u = ((unsigned)(unsigned short)s) << 16;
    return __builtin_bit_cast(float, u);
}
// tanh via exp: exact at both saturation ends; |err| ~1e-7 << bf16 rounding
static __device__ __forceinline__ float fast_tanh(float v) {
    float e = __expf(2.0f * v);
    return 1.0f - 2.0f / (e + 1.0f);
}

// -------- Phase 0: transpose f32 (K rows x N cols) -> bf16 (N rows x K cols) ----
__global__ __launch_bounds__(256) void transpose_f32_bf16(
    const float* __restrict__ in, short* __restrict__ out, int K, int N) {
    __shared__ short tile[64][65];
    int ntiles = N >> 6;
    int bn = blockIdx.x % ntiles;
    int bk = blockIdx.x / ntiles;
    int tid = threadIdx.x;
#pragma unroll
    for (int i = 0; i < 16; ++i) {
        int idx = i * 256 + tid;
        int lk = idx >> 6;
        int ln = idx & 63;
        float v = __builtin_nontemporal_load(
            &in[(size_t)(bk * 64 + lk) * N + (bn * 64 + ln)]);
        tile[ln][lk] = f2bf(v);
    }
    __syncthreads();
#pragma unroll
    for (int i = 0; i < 16; ++i) {
        int idx = i * 256 + tid;
        int lnr = idx >> 6;
        int lkc = idx & 63;
        out[(size_t)(bn * 64 + lnr) * K + (bk * 64 + lkc)] = tile[lnr][lkc];
    }
}

__global__ __launch_bounds__(256) void f32_to_bf16_vec(
    const float* __restrict__ in, short* __restrict__ out, int n) {
    int i = blockIdx.x * 256 + threadIdx.x;
    if (i < n) out[i] = f2bf(in[i]);
}

// -------- Phase 1: persistent recurrence, W in regs, own-slice via LDS ------
// 64 blocks x 256 thr, block (bgi,cgj) owns h[8*bgi..+8][64*cgj..+64].
// Own-produced tag words come from LDS (ownl) -- polling them via MALL lost a
// full ~900-cyc retry round every step (own store can't round-trip before the
// first poll sample). hl double-buffered; dual MFMA accumulator chains.
__global__ __launch_bounds__(256, 1) void rnn_persistent(
    const short* __restrict__ WhhT,   // (1024 n, 1024 k) bf16
    const float* __restrict__ Wxh,    // (VOCAB, 1024) f32
    const float* __restrict__ bh,     // (1024) f32
    const int*   __restrict__ x,      // (BATCH, SEQ) int32
    const short* __restrict__ S0,     // (32,1024) bf16 initial state
    short* __restrict__ H,            // (SEQ, 32, 1024) bf16 (plain, for gemm)
    u32* __restrict__ Htag)           // (2, 32, 1024) u32 tagged ping-pong
{
    __shared__ short hl[2][8 * 1024]; // 2 x 16 KB, XOR-swizzled granules
    __shared__ u32 ownl[8 * 64];      // 2 KB: own slice, tagged
    const int tid = threadIdx.x;
    const int bgi = blockIdx.x >> 4;  // 0..3  batch-row group
    const int cgj = blockIdx.x & 15;  // 0..15 column group
    const int grow0 = bgi * 8;
    const int gcol0 = cgj * 64;

    const int lane = tid & 63, wv_ = tid >> 6;
    const int lrow = lane & 15, kg = lane >> 4;
    const int rx = lrow & 7;
    const int gcol = gcol0 + wv_ * 16 + lrow;   // h column this lane produces
    const float bias = bh[gcol];
    const bool act = (kg < 2);

    // W_hh B-fragments -> registers (one-time)
    bf8v wreg[32];
#pragma unroll
    for (int it = 0; it < 32; ++it)
        wreg[it] = *(const bf8v*)(WhhT + ((size_t)gcol << 10) + it * 32 + kg * 8);

    // initial h rows from S0 -> hl[0]
    {
        const u64* s = (const u64*)(S0 + (grow0 << 10));
#pragma unroll
        for (int j = 0; j < 8; ++j) {
            int idx = tid + 256 * j;
            int r = idx >> 8, cq = idx & 255;
            u64 v = s[idx];
            *(u64*)((char*)hl[0] + (r << 11) + (((cq >> 1) ^ (r & 7)) << 4) + ((cq & 1) << 3)) = v;
        }
    }

    float wx[4] = {0.f, 0.f, 0.f, 0.f};
    if (act)
#pragma unroll
        for (int r = 0; r < 4; ++r) {
            int id = x[(grow0 + kg * 4 + r) * SEQ];
            wx[r] = Wxh[((size_t)id << 10) + gcol];
        }
    __syncthreads();

    int p = 0;   // hl[p] holds h_{t-1}
    for (int t = 0; t < SEQ; ++t) {
        const short* aBase = &hl[p][(lrow & 7) << 10];   // rows 8-15 dup 0-7

        // ---- MFMA, two independent accumulator chains ----
        f32x4 acc0 = {0.f, 0.f, 0.f, 0.f};
        f32x4 acc1 = {0.f, 0.f, 0.f, 0.f};
#pragma unroll
        for (int it = 0; it < 32; it += 2) {
            bf8v a0 = *(const bf8v*)(aBase + ((((4 * it) + kg) ^ rx) << 3));
            bf8v a1 = *(const bf8v*)(aBase + ((((4 * it + 4) + kg) ^ rx) << 3));
            acc0 = __builtin_amdgcn_mfma_f32_16x16x32_bf16(a0, wreg[it], acc0, 0, 0, 0);
            acc1 = __builtin_amdgcn_mfma_f32_16x16x32_bf16(a1, wreg[it + 1], acc1, 0, 0, 0);
        }

        // ---- tanh; tag stores first (latency-critical), then LDS own, H ----
        if (act) {
            const u32 wtag = (u32)(t + 1);
            u32* tagbuf = Htag + ((t & 1) << 15);
            short* Ht = H + ((size_t)t << 15);
            u32 tw[4];
#pragma unroll
            for (int r = 0; r < 4; ++r) {
                int grow = grow0 + kg * 4 + r;  // D map: col=lane&15, row=(lane>>4)*4+r
                float v = fast_tanh(wx[r] + acc0[r] + acc1[r] + bias);
                short bv = f2bf(v);
                tw[r] = ((u32)(unsigned short)bv << 16) | wtag;
                __hip_atomic_store(tagbuf + (grow << 10) + gcol, tw[r],
                                   __ATOMIC_RELAXED, __HIP_MEMORY_SCOPE_AGENT);
            }
#pragma unroll
            for (int r = 0; r < 4; ++r) {
                ownl[(kg * 4 + r) * 64 + (gcol - gcol0)] = tw[r];
                Ht[((grow0 + kg * 4 + r) << 10) + gcol] = (short)(tw[r] >> 16);
            }
        }

        if (t + 1 < SEQ) {
            // x + Wxh gather chain for t+1: issued here, consumed next step;
            // latency hides under barrier + poll + stage.
            if (act)
#pragma unroll
                for (int r = 0; r < 4; ++r) {
                    int id = x[(grow0 + kg * 4 + r) * SEQ + (t + 1)];
                    wx[r] = Wxh[((size_t)id << 10) + gcol];
                }

            // ownl visible to all waves before anyone reads it
            asm volatile("s_waitcnt lgkmcnt(0)" ::: "memory");
            __builtin_amdgcn_s_barrier();

            // ---- poll: own words from LDS, foreign words from MALL ----
            const u64 want = (u64)(u32)(t + 1) * 0x0000000100000001ull;
            const u64* base = (const u64*)(Htag + ((t & 1) << 15)) + (grow0 << 9);
            u64 vv[16];
#pragma unroll
            for (int j = 0; j < 16; ++j) {
                int idx = tid + 256 * j;
                int c2 = idx & 511, rr = idx >> 9;
                if ((c2 >> 5) == cgj) {
                    u64 lo = ownl[rr * 64 + (c2 & 31) * 2];
                    u64 hi = ownl[rr * 64 + (c2 & 31) * 2 + 1];
                    vv[j] = lo | (hi << 32);
                } else {
                    vv[j] = __hip_atomic_load(base + idx,
                                              __ATOMIC_RELAXED, __HIP_MEMORY_SCOPE_AGENT);
                }
            }
            for (;;) {
                bool ok = true;
#pragma unroll
                for (int j = 0; j < 16; ++j)
                    ok &= ((vv[j] & 0x0000FFFF0000FFFFull) == want);
                if (ok) break;
#pragma unroll
                for (int j = 0; j < 16; ++j) {
                    int idx = tid + 256 * j;
                    int c2 = idx & 511;
                    if ((c2 >> 5) != cgj)
                        vv[j] = __hip_atomic_load(base + idx,
                                                  __ATOMIC_RELAXED, __HIP_MEMORY_SCOPE_AGENT);
                }
            }

            // ---- strip tags, stage into hl[p^1] (hl[p] still valid) ----
            char* hb = (char*)hl[p ^ 1];
#pragma unroll
            for (int j = 0; j < 16; ++j) {
                int idx = tid + 256 * j;
                int r = idx >> 9, c2 = idx & 511;
                u32 pk = ((u32)(vv[j] >> 16) & 0xFFFFu) | ((u32)(vv[j] >> 32) & 0xFFFF0000u);
                *(u32*)(hb + (r << 11) + (((c2 >> 2) ^ (r & 7)) << 4) + ((c2 & 3) << 2)) = pk;
            }
            p ^= 1;
        }

        asm volatile("s_waitcnt lgkmcnt(0)" ::: "memory");
        __builtin_amdgcn_s_barrier();
        __builtin_amdgcn_sched_barrier(0);
    }
}

// -------- Phase 2: 256x256 double-buffered 4-phase GEMM (unchanged) ---------
__global__ __launch_bounds__(512, 2) void gemm_out(
    const short* __restrict__ A,
    const short* __restrict__ B,
    const float* __restrict__ bo,
    float* __restrict__ C)
{
    __shared__ __align__(16) char lds[139264];  // 128K bufs; 136K epi scratch

    int nwg = gridDim.x;
    int cpx = nwg >> 3;
    int bid = blockIdx.x;
    int swz = (bid & 7) * cpx + (bid >> 3);
    int bm = swz & 15;    // m fastest: consecutive blocks share the B panel
    int bn = swz >> 4;

    const int tid = threadIdx.x;
    const int lane = tid & 63;
    const int wid = tid >> 6;          // 0..7
    const int wm = wid >> 2;           // 0..1 (128-row M slice)
    const int wn = wid & 3;            // 0..3 (64-col N slice)
    const int lrow = lane & 15, kg = lane >> 4;
    const int rx = lrow & 7;

    const size_t a0 = (size_t)bm * 256;
    const size_t b0 = (size_t)bn * 256;

    const int srow8 = (lane >> 3) & 7;
    const int sxor = ((lane & 7) ^ srow8) << 3;   // element offset in 64-k row

    f32x4 acc[8][4] = {};

#define STAGEH(TT, HH)                                                        \
    {                                                                         \
        const short* gs_ = ((HH) < 2) ? A : B;                                \
        const size_t rb_ = (((HH) < 2) ? a0 : b0) + (size_t)((HH) & 1) * 128; \
        char* db_ = lds + (((HH) < 2) ? 0 : 65536) + ((TT) & 1) * 32768       \
                    + ((HH) & 1) * 16384 + wid * 1024;                        \
        const int kk_ = (TT) * 64;                                            \
        _Pragma("unroll")                                                     \
        for (int c_ = 0; c_ < 2; ++c_) {                                      \
            const short* src_ = gs_ + (rb_ + c_ * 64 + wid * 8 + srow8) * 1024\
                                + kk_ + sxor;                                 \
            __builtin_amdgcn_global_load_lds(                                 \
                (const __attribute__((address_space(1))) void*)src_,          \
                (__attribute__((address_space(3))) void*)(db_ + c_ * 8192),   \
                16, 0, 0);                                                    \
        }                                                                     \
    }

    STAGEH(0, 0); STAGEH(0, 1); STAGEH(0, 2); STAGEH(0, 3);

#pragma unroll 1
    for (int t = 0; t < 16; ++t) {
        __builtin_amdgcn_sched_barrier(0);
        __builtin_amdgcn_s_barrier();        // all waves done reading tile t-1
        __builtin_amdgcn_sched_barrier(0);
        if (t + 1 < 16) {
            STAGEH(t + 1, 0); STAGEH(t + 1, 1); STAGEH(t + 1, 2);   // 6 loads
            asm volatile("s_waitcnt vmcnt(6)" ::: "memory");        // tile t in
        } else {
            asm volatile("s_waitcnt vmcnt(0)" ::: "memory");
        }
        __builtin_amdgcn_sched_barrier(0);
        __builtin_amdgcn_s_barrier();        // tile t visible to all
        __builtin_amdgcn_sched_barrier(0);

        const char* Ab = lds + (t & 1) * 32768;
        const char* Bb = lds + 65536 + (t & 1) * 32768;

        bf8v bfr[4][2];
#pragma unroll
        for (int nj = 0; nj < 4; ++nj)
#pragma unroll
            for (int ks = 0; ks < 2; ++ks)
                bfr[nj][ks] = *(const bf8v*)(Bb + (wn * 64 + nj * 16 + lrow) * 128
                                             + ((((ks << 2) + kg) ^ rx) << 4));

#pragma unroll
        for (int q = 0; q < 4; ++q) {
            if (q == 1 && t + 1 < 16) STAGEH(t + 1, 3);
            bf8v af[2][2];
#pragma unroll
            for (int i = 0; i < 2; ++i)
#pragma unroll
                for (int ks = 0; ks < 2; ++ks)
                    af[i][ks] = *(const bf8v*)(Ab
                        + (wm * 128 + (q * 2 + i) * 16 + lrow) * 128
                        + ((((ks << 2) + kg) ^ rx) << 4));
            __builtin_amdgcn_sched_barrier(0);
            __builtin_amdgcn_s_setprio(1);
#pragma unroll
            for (int ks = 0; ks < 2; ++ks)
#pragma unroll
                for (int i = 0; i < 2; ++i)
#pragma unroll
                    for (int nj = 0; nj < 4; ++nj)
                        acc[q * 2 + i][nj] = __builtin_amdgcn_mfma_f32_16x16x32_bf16(
                            af[i][ks], bfr[nj][ks], acc[q * 2 + i][nj], 0, 0, 0);
            __builtin_amdgcn_s_setprio(0);
            __builtin_amdgcn_sched_barrier(0);
        }
    }
#undef STAGEH

    __builtin_amdgcn_sched_barrier(0);
    __builtin_amdgcn_s_barrier();            // all LDS buffer reads complete
    char* wbase = lds + wid * 17408;         // 64 rows x 272 B per wave
#pragma unroll
    for (int half = 0; half < 2; ++half) {
#pragma unroll
        for (int nj = 0; nj < 4; ++nj) {
            float bias = bo[b0 + wn * 64 + nj * 16 + lrow];
#pragma unroll
            for (int mi2 = 0; mi2 < 4; ++mi2)
#pragma unroll
                for (int r = 0; r < 4; ++r)
                    *(float*)(wbase + (mi2 * 16 + kg * 4 + r) * 272
                              + (nj * 16 + lrow) * 4)
                        = acc[half * 4 + mi2][nj][r] + bias;
        }
        asm volatile("s_waitcnt lgkmcnt(0)" ::: "memory");
        __builtin_amdgcn_sched_barrier(0);
#pragma unroll
        for (int p = 0; p < 16; ++p) {
            int lr = p * 4 + (lane >> 4);
            f32x4 v = *(const f32x4*)(wbase + lr * 272 + (lane & 15) * 16);
            size_t row_g = a0 + wm * 128 + half * 64 + lr;
            int col_g = (int)b0 + wn * 64 + (lane & 15) * 4;
            __builtin_nontemporal_store(v, (f32x4*)&C[row_g * VOCAB + col_g]);
        }
        asm volatile("s_waitcnt lgkmcnt(0)" ::: "memory");
        __builtin_amdgcn_sched_barrier(0);
    }
}

// -------- final_state: bf16 h_127 -> f32 ------------------------------------
__global__ __launch_bounds__(256) void write_final(
    const short* __restrict__ Hlast, float* __restrict__ out) {
    int i = blockIdx.x * 256 + threadIdx.x;
    if (i < BATCH * HIDDEN) out[i] = bf2f(Hlast[i]);
}

extern "C" void kernel_launch(void* const* d_in, const int* in_sizes, int n_in,
                              void* d_out, int out_size, void* d_ws, size_t ws_size,
                              hipStream_t stream) {
    const int*   x   = (const int*)  d_in[0];
    const float* st  = (const float*)d_in[1];
    const float* Wxh = (const float*)d_in[2];
    const float* Whh = (const float*)d_in[3];
    const float* bh  = (const float*)d_in[4];
    const float* Who = (const float*)d_in[5];
    const float* bo  = (const float*)d_in[6];
    float* out = (float*)d_out;

    char* ws = (char*)d_ws;
    short* WhhT = (short*)ws;                                           // 2 MB
    short* WhoT = (short*)(ws + 2097152ull);                            // 65.536 MB
    short* H    = (short*)(ws + 2097152ull + 65536000ull);              // 8.389 MB
    short* S0   = (short*)(ws + 2097152ull + 65536000ull + 8388608ull); // 64 KB
    u32*   Htag = (u32*)  (ws + 2097152ull + 65536000ull + 8388608ull + 65536ull); // 256 KB

    transpose_f32_bf16<<<(1024/64)*(1024/64), 256, 0, stream>>>(Whh, WhhT, 1024, 1024);
    transpose_f32_bf16<<<(VOCAB/64)*(1024/64), 256, 0, stream>>>(Who, WhoT, 1024, VOCAB);
    f32_to_bf16_vec<<<(BATCH*HIDDEN + 255)/256, 256, 0, stream>>>(st, S0, BATCH*HIDDEN);
    hipMemsetAsync(Htag, 0, 2ull * BATCH * HIDDEN * sizeof(u32), stream);

    rnn_persistent<<<64, 256, 0, stream>>>(WhhT, Wxh, bh, x, S0, H, Htag);

    gemm_out<<<(4096/256) * (VOCAB/256), 512, 0, stream>>>(H, WhoT, bo, out);
    write_final<<<(BATCH*HIDDEN + 255)/256, 256, 0, stream>>>(
        H + (size_t)(SEQ - 1) * BATCH * HIDDEN, out + (size_t)SEQ * BATCH * VOCAB);
}

// Round 12
// 692.443 us; speedup vs baseline: 1.2423x; 1.2423x over previous
//
#include <hip/hip_runtime.h>
#include <hip/hip_bf16.h>

#define VOCAB 32000
#define HIDDEN 1024
#define BATCH 32
#define SEQ 128

typedef short bf8v __attribute__((ext_vector_type(8)));   // 8 x bf16 payload
typedef float f32x4 __attribute__((ext_vector_type(4)));
typedef unsigned long long u64;
typedef unsigned int u32;

static __device__ __forceinline__ short f2bf(float f) {
    return __builtin_bit_cast(short, __float2bfloat16(f));
}
static __device__ __forceinline__ float bf2f(short s) {
    unsigned u = ((unsigned)(unsigned short)s) << 16;
    return __builtin_bit_cast(float, u);
}
// tanh via exp: exact at both saturation ends; |err| ~1e-7 << bf16 rounding
static __device__ __forceinline__ float fast_tanh(float v) {
    float e = __expf(2.0f * v);
    return 1.0f - 2.0f / (e + 1.0f);
}

// -------- Phase 0: transpose f32 (K rows x N cols) -> bf16 (N rows x K cols) ----
__global__ __launch_bounds__(256) void transpose_f32_bf16(
    const float* __restrict__ in, short* __restrict__ out, int K, int N) {
    __shared__ short tile[64][65];
    int ntiles = N >> 6;
    int bn = blockIdx.x % ntiles;
    int bk = blockIdx.x / ntiles;
    int tid = threadIdx.x;
#pragma unroll
    for (int i = 0; i < 16; ++i) {
        int idx = i * 256 + tid;
        int lk = idx >> 6;
        int ln = idx & 63;
        float v = __builtin_nontemporal_load(
            &in[(size_t)(bk * 64 + lk) * N + (bn * 64 + ln)]);
        tile[ln][lk] = f2bf(v);
    }
    __syncthreads();
#pragma unroll
    for (int i = 0; i < 16; ++i) {
        int idx = i * 256 + tid;
        int lnr = idx >> 6;
        int lkc = idx & 63;
        out[(size_t)(bn * 64 + lnr) * K + (bk * 64 + lkc)] = tile[lnr][lkc];
    }
}

__global__ __launch_bounds__(256) void f32_to_bf16_vec(
    const float* __restrict__ in, short* __restrict__ out, int n) {
    int i = blockIdx.x * 256 + threadIdx.x;
    if (i < n) out[i] = f2bf(in[i]);
}

// -------- Phase 1: persistent recurrence (r10 structure + 3 contained deltas)
// 64 blocks x 256 thr, block (bgi,cgj) owns h[8*bgi..+8][64*cgj..+64].
// r10-proven: poll starts immediately after own stores (no pre-poll barrier);
// 16 unconditional batched tag loads; retry-all. Deltas vs r10:
//  (1) dual MFMA accumulator chains (halve serial dep)
//  (2) check masks own words (per-thread uniform bools, static j selection);
//      correct own values spliced from ownl LDS after the post-poll barrier
//  (3) explicit lgkmcnt(0) before that barrier (LDS-visibility formality)
__global__ __launch_bounds__(256, 1) void rnn_persistent(
    const short* __restrict__ WhhT,   // (1024 n, 1024 k) bf16
    const float* __restrict__ Wxh,    // (VOCAB, 1024) f32
    const float* __restrict__ bh,     // (1024) f32
    const int*   __restrict__ x,      // (BATCH, SEQ) int32
    const short* __restrict__ S0,     // (32,1024) bf16 initial state
    short* __restrict__ H,            // (SEQ, 32, 1024) bf16 (plain, for gemm)
    u32* __restrict__ Htag)           // (2, 32, 1024) u32 tagged ping-pong
{
    __shared__ short hl[8 * 1024];    // 16 KB: 8 batch rows x 1024 k, XOR-swizzled
    __shared__ u32 ownl[8 * 64];      // 2 KB: own slice, tagged
    const int tid = threadIdx.x;
    const int bgi = blockIdx.x >> 4;  // 0..3  batch-row group
    const int cgj = blockIdx.x & 15;  // 0..15 column group
    const int grow0 = bgi * 8;
    const int gcol0 = cgj * 64;

    const int lane = tid & 63, wv_ = tid >> 6;
    const int lrow = lane & 15, kg = lane >> 4;
    const int rx = lrow & 7;
    const int gcol = gcol0 + wv_ * 16 + lrow;   // h column this lane produces
    const float bias = bh[gcol];
    const short* aBase = hl + ((lrow & 7) << 10);   // rows 8-15 alias 0-7 (dup)
    const bool act = (kg < 2);
    // this thread's even-j poll words (c2 = tid) are own iff tid>>5 == cgj;
    // odd-j words (c2 = tid+256) own iff tid>>5 == cgj-8. Uniform per thread.
    const bool ownE = ((tid >> 5) == cgj);
    const bool ownO = ((tid >> 5) == cgj - 8);

    // W_hh B-fragments -> registers (one-time)
    bf8v wreg[32];
#pragma unroll
    for (int it = 0; it < 32; ++it)
        wreg[it] = *(const bf8v*)(WhhT + ((size_t)gcol << 10) + it * 32 + kg * 8);

    // initial h rows from S0 -> hl
    {
        const u64* s = (const u64*)(S0 + (grow0 << 10));
#pragma unroll
        for (int j = 0; j < 8; ++j) {
            int idx = tid + 256 * j;
            int r = idx >> 8, cq = idx & 255;
            u64 v = s[idx];
            *(u64*)((char*)hl + (r << 11) + (((cq >> 1) ^ (r & 7)) << 4) + ((cq & 1) << 3)) = v;
        }
    }

    float wx[4] = {0.f, 0.f, 0.f, 0.f};
    if (act)
#pragma unroll
        for (int r = 0; r < 4; ++r) {
            int id = x[(grow0 + kg * 4 + r) * SEQ];
            wx[r] = Wxh[((size_t)id << 10) + gcol];
        }
    __syncthreads();

    for (int t = 0; t < SEQ; ++t) {
        // ---- MFMA on h_{t-1}, two independent accumulator chains ----
        f32x4 acc0 = {0.f, 0.f, 0.f, 0.f};
        f32x4 acc1 = {0.f, 0.f, 0.f, 0.f};
#pragma unroll
        for (int it = 0; it < 32; it += 2) {
            bf8v a0 = *(const bf8v*)(aBase + (((4 * it + kg) ^ rx) << 3));
            bf8v a1 = *(const bf8v*)(aBase + (((4 * it + 4 + kg) ^ rx) << 3));
            acc0 = __builtin_amdgcn_mfma_f32_16x16x32_bf16(a0, wreg[it], acc0, 0, 0, 0);
            acc1 = __builtin_amdgcn_mfma_f32_16x16x32_bf16(a1, wreg[it + 1], acc1, 0, 0, 0);
        }

        // ---- tanh + tagged store (MALL) + ownl (LDS) + plain H store ----
        if (act) {
            const u32 wtag = (u32)(t + 1);
            u32* tagbuf = Htag + ((t & 1) << 15);
            short* Ht = H + ((size_t)t << 15);
            u32 tw[4];
#pragma unroll
            for (int r = 0; r < 4; ++r) {
                int grow = grow0 + kg * 4 + r;  // D map: col=lane&15, row=(lane>>4)*4+r
                float v = fast_tanh(wx[r] + acc0[r] + acc1[r] + bias);
                short bv = f2bf(v);
                tw[r] = ((u32)(unsigned short)bv << 16) | wtag;
                __hip_atomic_store(tagbuf + (grow << 10) + gcol, tw[r],
                                   __ATOMIC_RELAXED, __HIP_MEMORY_SCOPE_AGENT);
                Ht[(grow << 10) + gcol] = bv;
            }
#pragma unroll
            for (int r = 0; r < 4; ++r)
                ownl[(kg * 4 + r) * 64 + (wv_ * 16 + lrow)] = tw[r];
        }

        if (t + 1 < SEQ) {
            // x + Wxh gather chain for t+1 (latency hides under poll)
            if (act)
#pragma unroll
                for (int r = 0; r < 4; ++r) {
                    int id = x[(grow0 + kg * 4 + r) * SEQ + (t + 1)];
                    wx[r] = Wxh[((size_t)id << 10) + gcol];
                }

            // ---- poll (r10 codegen: 16 unconditional batched loads) ----
            const u64 want = (u64)(u32)(t + 1) * 0x0000000100000001ull;
            const u64* base = (const u64*)(Htag + ((t & 1) << 15)) + (grow0 << 9);
            u64 vv[16];
#pragma unroll
            for (int j = 0; j < 16; ++j)
                vv[j] = __hip_atomic_load(base + tid + 256 * j,
                                          __ATOMIC_RELAXED, __HIP_MEMORY_SCOPE_AGENT);
            for (;;) {
                bool ok = true;
#pragma unroll
                for (int j = 0; j < 16; ++j) {
                    bool own = (j & 1) ? ownO : ownE;   // static j -> uniform bool
                    ok &= own | ((vv[j] & 0x0000FFFF0000FFFFull) == want);
                }
                if (ok) break;
#pragma unroll
                for (int j = 0; j < 16; ++j)
                    vv[j] = __hip_atomic_load(base + tid + 256 * j,
                                              __ATOMIC_RELAXED, __HIP_MEMORY_SCOPE_AGENT);
            }

            // ownl writes drained, then: all waves past MFMA reads of hl,
            // and ownl visible for the splice below.
            asm volatile("s_waitcnt lgkmcnt(0)" ::: "memory");
            __builtin_amdgcn_s_barrier();

            // ---- splice own words from LDS (never wait on own MALL trip) ----
            if (ownE) {
                int off = (tid & 31) * 2;
#pragma unroll
                for (int rr = 0; rr < 8; ++rr) {
                    u64 lo = ownl[rr * 64 + off];
                    u64 hi = ownl[rr * 64 + off + 1];
                    vv[2 * rr] = lo | (hi << 32);
                }
            } else if (ownO) {
                int off = (tid & 31) * 2;
#pragma unroll
                for (int rr = 0; rr < 8; ++rr) {
                    u64 lo = ownl[rr * 64 + off];
                    u64 hi = ownl[rr * 64 + off + 1];
                    vv[2 * rr + 1] = lo | (hi << 32);
                }
            }

            // ---- strip tags, stage into hl (swizzled) ----
#pragma unroll
            for (int j = 0; j < 16; ++j) {
                int idx = tid + 256 * j;
                int r = idx >> 9, c2 = idx & 511;
                u32 pk = ((u32)(vv[j] >> 16) & 0xFFFFu) | ((u32)(vv[j] >> 32) & 0xFFFF0000u);
                *(u32*)((char*)hl + (r << 11) + (((c2 >> 2) ^ (r & 7)) << 4) + ((c2 & 3) << 2)) = pk;
            }
        }

        asm volatile("s_waitcnt lgkmcnt(0)" ::: "memory");
        __builtin_amdgcn_s_barrier();
        __builtin_amdgcn_sched_barrier(0);
    }
}

// -------- Phase 2: 256x256 double-buffered 4-phase GEMM (unchanged, proven) --
__global__ __launch_bounds__(512, 2) void gemm_out(
    const short* __restrict__ A,
    const short* __restrict__ B,
    const float* __restrict__ bo,
    float* __restrict__ C)
{
    __shared__ __align__(16) char lds[139264];  // 128K bufs; 136K epi scratch

    int nwg = gridDim.x;
    int cpx = nwg >> 3;
    int bid = blockIdx.x;
    int swz = (bid & 7) * cpx + (bid >> 3);
    int bm = swz & 15;    // m fastest: consecutive blocks share the B panel
    int bn = swz >> 4;

    const int tid = threadIdx.x;
    const int lane = tid & 63;
    const int wid = tid >> 6;          // 0..7
    const int wm = wid >> 2;           // 0..1 (128-row M slice)
    const int wn = wid & 3;            // 0..3 (64-col N slice)
    const int lrow = lane & 15, kg = lane >> 4;
    const int rx = lrow & 7;

    const size_t a0 = (size_t)bm * 256;
    const size_t b0 = (size_t)bn * 256;

    const int srow8 = (lane >> 3) & 7;
    const int sxor = ((lane & 7) ^ srow8) << 3;   // element offset in 64-k row

    f32x4 acc[8][4] = {};

#define STAGEH(TT, HH)                                                        \
    {                                                                         \
        const short* gs_ = ((HH) < 2) ? A : B;                                \
        const size_t rb_ = (((HH) < 2) ? a0 : b0) + (size_t)((HH) & 1) * 128; \
        char* db_ = lds + (((HH) < 2) ? 0 : 65536) + ((TT) & 1) * 32768       \
                    + ((HH) & 1) * 16384 + wid * 1024;                        \
        const int kk_ = (TT) * 64;                                            \
        _Pragma("unroll")                                                     \
        for (int c_ = 0; c_ < 2; ++c_) {                                      \
            const short* src_ = gs_ + (rb_ + c_ * 64 + wid * 8 + srow8) * 1024\
                                + kk_ + sxor;                                 \
            __builtin_amdgcn_global_load_lds(                                 \
                (const __attribute__((address_space(1))) void*)src_,          \
                (__attribute__((address_space(3))) void*)(db_ + c_ * 8192),   \
                16, 0, 0);                                                    \
        }                                                                     \
    }

    STAGEH(0, 0); STAGEH(0, 1); STAGEH(0, 2); STAGEH(0, 3);

#pragma unroll 1
    for (int t = 0; t < 16; ++t) {
        __builtin_amdgcn_sched_barrier(0);
        __builtin_amdgcn_s_barrier();        // all waves done reading tile t-1
        __builtin_amdgcn_sched_barrier(0);
        if (t + 1 < 16) {
            STAGEH(t + 1, 0); STAGEH(t + 1, 1); STAGEH(t + 1, 2);   // 6 loads
            asm volatile("s_waitcnt vmcnt(6)" ::: "memory");        // tile t in
        } else {
            asm volatile("s_waitcnt vmcnt(0)" ::: "memory");
        }
        __builtin_amdgcn_sched_barrier(0);
        __builtin_amdgcn_s_barrier();        // tile t visible to all
        __builtin_amdgcn_sched_barrier(0);

        const char* Ab = lds + (t & 1) * 32768;
        const char* Bb = lds + 65536 + (t & 1) * 32768;

        bf8v bfr[4][2];
#pragma unroll
        for (int nj = 0; nj < 4; ++nj)
#pragma unroll
            for (int ks = 0; ks < 2; ++ks)
                bfr[nj][ks] = *(const bf8v*)(Bb + (wn * 64 + nj * 16 + lrow) * 128
                                             + ((((ks << 2) + kg) ^ rx) << 4));

#pragma unroll
        for (int q = 0; q < 4; ++q) {
            if (q == 1 && t + 1 < 16) STAGEH(t + 1, 3);
            bf8v af[2][2];
#pragma unroll
            for (int i = 0; i < 2; ++i)
#pragma unroll
                for (int ks = 0; ks < 2; ++ks)
                    af[i][ks] = *(const bf8v*)(Ab
                        + (wm * 128 + (q * 2 + i) * 16 + lrow) * 128
                        + ((((ks << 2) + kg) ^ rx) << 4));
            __builtin_amdgcn_sched_barrier(0);
            __builtin_amdgcn_s_setprio(1);
#pragma unroll
            for (int ks = 0; ks < 2; ++ks)
#pragma unroll
                for (int i = 0; i < 2; ++i)
#pragma unroll
                    for (int nj = 0; nj < 4; ++nj)
                        acc[q * 2 + i][nj] = __builtin_amdgcn_mfma_f32_16x16x32_bf16(
                            af[i][ks], bfr[nj][ks], acc[q * 2 + i][nj], 0, 0, 0);
            __builtin_amdgcn_s_setprio(0);
            __builtin_amdgcn_sched_barrier(0);
        }
    }
#undef STAGEH

    __builtin_amdgcn_sched_barrier(0);
    __builtin_amdgcn_s_barrier();            // all LDS buffer reads complete
    char* wbase = lds + wid * 17408;         // 64 rows x 272 B per wave
#pragma unroll
    for (int half = 0; half < 2; ++half) {
#pragma unroll
        for (int nj = 0; nj < 4; ++nj) {
            float bias = bo[b0 + wn * 64 + nj * 16 + lrow];
#pragma unroll
            for (int mi2 = 0; mi2 < 4; ++mi2)
#pragma unroll
                for (int r = 0; r < 4; ++r)
                    *(float*)(wbase + (mi2 * 16 + kg * 4 + r) * 272
                              + (nj * 16 + lrow) * 4)
                        = acc[half * 4 + mi2][nj][r] + bias;
        }
        asm volatile("s_waitcnt lgkmcnt(0)" ::: "memory");
        __builtin_amdgcn_sched_barrier(0);
#pragma unroll
        for (int p = 0; p < 16; ++p) {
            int lr = p * 4 + (lane >> 4);
            f32x4 v = *(const f32x4*)(wbase + lr * 272 + (lane & 15) * 16);
            size_t row_g = a0 + wm * 128 + half * 64 + lr;
            int col_g = (int)b0 + wn * 64 + (lane & 15) * 4;
            __builtin_nontemporal_store(v, (f32x4*)&C[row_g * VOCAB + col_g]);
        }
        asm volatile("s_waitcnt lgkmcnt(0)" ::: "memory");
        __builtin_amdgcn_sched_barrier(0);
    }
}

// -------- final_state: bf16 h_127 -> f32 ------------------------------------
__global__ __launch_bounds__(256) void write_final(
    const short* __restrict__ Hlast, float* __restrict__ out) {
    int i = blockIdx.x * 256 + threadIdx.x;
    if (i < BATCH * HIDDEN) out[i] = bf2f(Hlast[i]);
}

extern "C" void kernel_launch(void* const* d_in, const int* in_sizes, int n_in,
                              void* d_out, int out_size, void* d_ws, size_t ws_size,
                              hipStream_t stream) {
    const int*   x   = (const int*)  d_in[0];
    const float* st  = (const float*)d_in[1];
    const float* Wxh = (const float*)d_in[2];
    const float* Whh = (const float*)d_in[3];
    const float* bh  = (const float*)d_in[4];
    const float* Who = (const float*)d_in[5];
    const float* bo  = (const float*)d_in[6];
    float* out = (float*)d_out;

    char* ws = (char*)d_ws;
    short* WhhT = (short*)ws;                                           // 2 MB
    short* WhoT = (short*)(ws + 2097152ull);                            // 65.536 MB
    short* H    = (short*)(ws + 2097152ull + 65536000ull);              // 8.389 MB
    short* S0   = (short*)(ws + 2097152ull + 65536000ull + 8388608ull); // 64 KB
    u32*   Htag = (u32*)  (ws + 2097152ull + 65536000ull + 8388608ull + 65536ull); // 256 KB

    transpose_f32_bf16<<<(1024/64)*(1024/64), 256, 0, stream>>>(Whh, WhhT, 1024, 1024);
    transpose_f32_bf16<<<(VOCAB/64)*(1024/64), 256, 0, stream>>>(Who, WhoT, 1024, VOCAB);
    f32_to_bf16_vec<<<(BATCH*HIDDEN + 255)/256, 256, 0, stream>>>(st, S0, BATCH*HIDDEN);
    hipMemsetAsync(Htag, 0, 2ull * BATCH * HIDDEN * sizeof(u32), stream);

    rnn_persistent<<<64, 256, 0, stream>>>(WhhT, Wxh, bh, x, S0, H, Htag);

    gemm_out<<<(4096/256) * (VOCAB/256), 512, 0, stream>>>(H, WhoT, bo, out);
    write_final<<<(BATCH*HIDDEN + 255)/256, 256, 0, stream>>>(
        H + (size_t)(SEQ - 1) * BATCH * HIDDEN, out + (size_t)SEQ * BATCH * VOCAB);
}

// Round 13
// 615.013 us; speedup vs baseline: 1.3988x; 1.1259x over previous
//
#include <hip/hip_runtime.h>
#include <hip/hip_bf16.h>

#define VOCAB 32000
#define HIDDEN 1024
#define BATCH 32
#define SEQ 128

typedef short bf8v __attribute__((ext_vector_type(8)));   // 8 x bf16 payload
typedef float f32x4 __attribute__((ext_vector_type(4)));
typedef unsigned long long u64;
typedef unsigned int u32;

static __device__ __forceinline__ short f2bf(float f) {
    return __builtin_bit_cast(short, __float2bfloat16(f));
}
static __device__ __forceinline__ float bf2f(short s) {
    unsigned u = ((unsigned)(unsigned short)s) << 16;
    return __builtin_bit_cast(float, u);
}
// tanh via exp: exact at both saturation ends; |err| ~1e-7 << bf16 rounding
static __device__ __forceinline__ float fast_tanh(float v) {
    float e = __expf(2.0f * v);
    return 1.0f - 2.0f / (e + 1.0f);
}

// -------- Phase 0: transpose f32 (K rows x N cols) -> bf16 (N rows x K cols) ----
__global__ __launch_bounds__(256) void transpose_f32_bf16(
    const float* __restrict__ in, short* __restrict__ out, int K, int N) {
    __shared__ short tile[64][65];
    int ntiles = N >> 6;
    int bn = blockIdx.x % ntiles;
    int bk = blockIdx.x / ntiles;
    int tid = threadIdx.x;
#pragma unroll
    for (int i = 0; i < 16; ++i) {
        int idx = i * 256 + tid;
        int lk = idx >> 6;
        int ln = idx & 63;
        float v = __builtin_nontemporal_load(
            &in[(size_t)(bk * 64 + lk) * N + (bn * 64 + ln)]);
        tile[ln][lk] = f2bf(v);
    }
    __syncthreads();
#pragma unroll
    for (int i = 0; i < 16; ++i) {
        int idx = i * 256 + tid;
        int lnr = idx >> 6;
        int lkc = idx & 63;
        out[(size_t)(bn * 64 + lnr) * K + (bk * 64 + lkc)] = tile[lnr][lkc];
    }
}

__global__ __launch_bounds__(256) void f32_to_bf16_vec(
    const float* __restrict__ in, short* __restrict__ out, int n) {
    int i = blockIdx.x * 256 + threadIdx.x;
    if (i < n) out[i] = f2bf(in[i]);
}

// -------- Phase 1: persistent recurrence, W in regs (EXACT round-10 version,
// measured 324 us). 64 blocks x 256 thr, block (bgi,cgj) owns
// h[8*bgi..+8][64*cgj..+64]. Depth-2 tagged ping-pong, parallel poll
// (retry-all), poll starts immediately after own stores, single hl buffer,
// single accumulator chain. Two failed "improvements" (r11: pre-poll barrier
// + divergent poll; r12: dual chains + own-word splice) bracket this as the
// local optimum -- do not perturb the inner loop's register allocation.
__global__ __launch_bounds__(256, 1) void rnn_persistent(
    const short* __restrict__ WhhT,   // (1024 n, 1024 k) bf16
    const float* __restrict__ Wxh,    // (VOCAB, 1024) f32
    const float* __restrict__ bh,     // (1024) f32
    const int*   __restrict__ x,      // (BATCH, SEQ) int32
    const short* __restrict__ S0,     // (32,1024) bf16 initial state
    short* __restrict__ H,            // (SEQ, 32, 1024) bf16 (plain, for gemm)
    u32* __restrict__ Htag)           // (2, 32, 1024) u32 tagged ping-pong
{
    __shared__ short hl[8 * 1024];    // 16 KB: 8 batch rows x 1024 k, XOR-swizzled
    const int tid = threadIdx.x;
    const int bgi = blockIdx.x >> 4;  // 0..3  batch-row group
    const int cgj = blockIdx.x & 15;  // 0..15 column group
    const int grow0 = bgi * 8;
    const int gcol0 = cgj * 64;

    const int lane = tid & 63, wv_ = tid >> 6;
    const int lrow = lane & 15, kg = lane >> 4;
    const int rx = lrow & 7;
    const int gcol = gcol0 + wv_ * 16 + lrow;   // h column this lane produces
    const float bias = bh[gcol];
    const short* aBase = hl + ((lrow & 7) << 10);   // rows 8-15 alias 0-7 (dup)
    const bool act = (kg < 2);

    // W_hh B-fragments -> registers (one-time)
    bf8v wreg[32];
#pragma unroll
    for (int it = 0; it < 32; ++it)
        wreg[it] = *(const bf8v*)(WhhT + ((size_t)gcol << 10) + it * 32 + kg * 8);

    // initial h rows from S0 -> hl
    {
        const u64* s = (const u64*)(S0 + (grow0 << 10));
#pragma unroll
        for (int j = 0; j < 8; ++j) {
            int idx = tid + 256 * j;
            int r = idx >> 8, cq = idx & 255;
            u64 v = s[idx];
            *(u64*)((char*)hl + (r << 11) + (((cq >> 1) ^ (r & 7)) << 4) + ((cq & 1) << 3)) = v;
        }
    }

    float wx[4] = {0.f, 0.f, 0.f, 0.f};
    if (act)
#pragma unroll
        for (int r = 0; r < 4; ++r) {
            int id = x[(grow0 + kg * 4 + r) * SEQ];
            wx[r] = Wxh[((size_t)id << 10) + gcol];
        }
    __syncthreads();

    for (int t = 0; t < SEQ; ++t) {
        f32x4 acc = {0.f, 0.f, 0.f, 0.f};
#pragma unroll
        for (int it = 0; it < 32; ++it) {
            int off = ((4 * it + kg) ^ rx) << 3;
            bf8v a = *(const bf8v*)(aBase + off);
            acc = __builtin_amdgcn_mfma_f32_16x16x32_bf16(a, wreg[it], acc, 0, 0, 0);
        }

        if (act) {
            const u32 wtag = (u32)(t + 1);
            u32* tagbuf = Htag + ((t & 1) << 15);
            short* Ht = H + ((size_t)t << 15);
#pragma unroll
            for (int r = 0; r < 4; ++r) {
                int grow = grow0 + kg * 4 + r;
                float v = fast_tanh(wx[r] + acc[r] + bias);
                short bv = f2bf(v);
                __hip_atomic_store(tagbuf + (grow << 10) + gcol,
                                   ((u32)(unsigned short)bv << 16) | wtag,
                                   __ATOMIC_RELAXED, __HIP_MEMORY_SCOPE_AGENT);
                Ht[(grow << 10) + gcol] = bv;
            }
        }

        if (t + 1 < SEQ) {
            if (act)
#pragma unroll
                for (int r = 0; r < 4; ++r) {
                    int id = x[(grow0 + kg * 4 + r) * SEQ + (t + 1)];
                    wx[r] = Wxh[((size_t)id << 10) + gcol];
                }

            const u64 want = (u64)(u32)(t + 1) * 0x0000000100000001ull;
            const u64* base = (const u64*)(Htag + ((t & 1) << 15)) + (grow0 << 9);
            u64 vv[16];
#pragma unroll
            for (int j = 0; j < 16; ++j)
                vv[j] = __hip_atomic_load(base + tid + 256 * j,
                                          __ATOMIC_RELAXED, __HIP_MEMORY_SCOPE_AGENT);
            for (;;) {
                bool ok = true;
#pragma unroll
                for (int j = 0; j < 16; ++j)
                    ok &= ((vv[j] & 0x0000FFFF0000FFFFull) == want);
                if (ok) break;
#pragma unroll
                for (int j = 0; j < 16; ++j)
                    vv[j] = __hip_atomic_load(base + tid + 256 * j,
                                              __ATOMIC_RELAXED, __HIP_MEMORY_SCOPE_AGENT);
            }

            __builtin_amdgcn_s_barrier();   // all waves past MFMA reads of hl

#pragma unroll
            for (int j = 0; j < 16; ++j) {
                int idx = tid + 256 * j;
                int r = idx >> 9, c2 = idx & 511;
                u32 pk = ((u32)(vv[j] >> 16) & 0xFFFFu) | ((u32)(vv[j] >> 32) & 0xFFFF0000u);
                *(u32*)((char*)hl + (r << 11) + (((c2 >> 2) ^ (r & 7)) << 4) + ((c2 & 3) << 2)) = pk;
            }
        }

        asm volatile("s_waitcnt lgkmcnt(0)" ::: "memory");
        __builtin_amdgcn_s_barrier();
        __builtin_amdgcn_sched_barrier(0);
    }
}

// -------- Phase 2: 256x256 double-buffered 4-phase GEMM (unchanged, proven) --
__global__ __launch_bounds__(512, 2) void gemm_out(
    const short* __restrict__ A,
    const short* __restrict__ B,
    const float* __restrict__ bo,
    float* __restrict__ C)
{
    __shared__ __align__(16) char lds[139264];  // 128K bufs; 136K epi scratch

    int nwg = gridDim.x;
    int cpx = nwg >> 3;
    int bid = blockIdx.x;
    int swz = (bid & 7) * cpx + (bid >> 3);
    int bm = swz & 15;    // m fastest: consecutive blocks share the B panel
    int bn = swz >> 4;

    const int tid = threadIdx.x;
    const int lane = tid & 63;
    const int wid = tid >> 6;          // 0..7
    const int wm = wid >> 2;           // 0..1 (128-row M slice)
    const int wn = wid & 3;            // 0..3 (64-col N slice)
    const int lrow = lane & 15, kg = lane >> 4;
    const int rx = lrow & 7;

    const size_t a0 = (size_t)bm * 256;
    const size_t b0 = (size_t)bn * 256;

    const int srow8 = (lane >> 3) & 7;
    const int sxor = ((lane & 7) ^ srow8) << 3;   // element offset in 64-k row

    f32x4 acc[8][4] = {};

#define STAGEH(TT, HH)                                                        \
    {                                                                         \
        const short* gs_ = ((HH) < 2) ? A : B;                                \
        const size_t rb_ = (((HH) < 2) ? a0 : b0) + (size_t)((HH) & 1) * 128; \
        char* db_ = lds + (((HH) < 2) ? 0 : 65536) + ((TT) & 1) * 32768       \
                    + ((HH) & 1) * 16384 + wid * 1024;                        \
        const int kk_ = (TT) * 64;                                            \
        _Pragma("unroll")                                                     \
        for (int c_ = 0; c_ < 2; ++c_) {                                      \
            const short* src_ = gs_ + (rb_ + c_ * 64 + wid * 8 + srow8) * 1024\
                                + kk_ + sxor;                                 \
            __builtin_amdgcn_global_load_lds(                                 \
                (const __attribute__((address_space(1))) void*)src_,          \
                (__attribute__((address_space(3))) void*)(db_ + c_ * 8192),   \
                16, 0, 0);                                                    \
        }                                                                     \
    }

    STAGEH(0, 0); STAGEH(0, 1); STAGEH(0, 2); STAGEH(0, 3);

#pragma unroll 1
    for (int t = 0; t < 16; ++t) {
        __builtin_amdgcn_sched_barrier(0);
        __builtin_amdgcn_s_barrier();        // all waves done reading tile t-1
        __builtin_amdgcn_sched_barrier(0);
        if (t + 1 < 16) {
            STAGEH(t + 1, 0); STAGEH(t + 1, 1); STAGEH(t + 1, 2);   // 6 loads
            asm volatile("s_waitcnt vmcnt(6)" ::: "memory");        // tile t in
        } else {
            asm volatile("s_waitcnt vmcnt(0)" ::: "memory");
        }
        __builtin_amdgcn_sched_barrier(0);
        __builtin_amdgcn_s_barrier();        // tile t visible to all
        __builtin_amdgcn_sched_barrier(0);

        const char* Ab = lds + (t & 1) * 32768;
        const char* Bb = lds + 65536 + (t & 1) * 32768;

        bf8v bfr[4][2];
#pragma unroll
        for (int nj = 0; nj < 4; ++nj)
#pragma unroll
            for (int ks = 0; ks < 2; ++ks)
                bfr[nj][ks] = *(const bf8v*)(Bb + (wn * 64 + nj * 16 + lrow) * 128
                                             + ((((ks << 2) + kg) ^ rx) << 4));

#pragma unroll
        for (int q = 0; q < 4; ++q) {
            if (q == 1 && t + 1 < 16) STAGEH(t + 1, 3);
            bf8v af[2][2];
#pragma unroll
            for (int i = 0; i < 2; ++i)
#pragma unroll
                for (int ks = 0; ks < 2; ++ks)
                    af[i][ks] = *(const bf8v*)(Ab
                        + (wm * 128 + (q * 2 + i) * 16 + lrow) * 128
                        + ((((ks << 2) + kg) ^ rx) << 4));
            __builtin_amdgcn_sched_barrier(0);
            __builtin_amdgcn_s_setprio(1);
#pragma unroll
            for (int ks = 0; ks < 2; ++ks)
#pragma unroll
                for (int i = 0; i < 2; ++i)
#pragma unroll
                    for (int nj = 0; nj < 4; ++nj)
                        acc[q * 2 + i][nj] = __builtin_amdgcn_mfma_f32_16x16x32_bf16(
                            af[i][ks], bfr[nj][ks], acc[q * 2 + i][nj], 0, 0, 0);
            __builtin_amdgcn_s_setprio(0);
            __builtin_amdgcn_sched_barrier(0);
        }
    }
#undef STAGEH

    __builtin_amdgcn_sched_barrier(0);
    __builtin_amdgcn_s_barrier();            // all LDS buffer reads complete
    char* wbase = lds + wid * 17408;         // 64 rows x 272 B per wave
#pragma unroll
    for (int half = 0; half < 2; ++half) {
#pragma unroll
        for (int nj = 0; nj < 4; ++nj) {
            float bias = bo[b0 + wn * 64 + nj * 16 + lrow];
#pragma unroll
            for (int mi2 = 0; mi2 < 4; ++mi2)
#pragma unroll
                for (int r = 0; r < 4; ++r)
                    *(float*)(wbase + (mi2 * 16 + kg * 4 + r) * 272
                              + (nj * 16 + lrow) * 4)
                        = acc[half * 4 + mi2][nj][r] + bias;
        }
        asm volatile("s_waitcnt lgkmcnt(0)" ::: "memory");
        __builtin_amdgcn_sched_barrier(0);
#pragma unroll
        for (int p = 0; p < 16; ++p) {
            int lr = p * 4 + (lane >> 4);
            f32x4 v = *(const f32x4*)(wbase + lr * 272 + (lane & 15) * 16);
            size_t row_g = a0 + wm * 128 + half * 64 + lr;
            int col_g = (int)b0 + wn * 64 + (lane & 15) * 4;
            __builtin_nontemporal_store(v, (f32x4*)&C[row_g * VOCAB + col_g]);
        }
        asm volatile("s_waitcnt lgkmcnt(0)" ::: "memory");
        __builtin_amdgcn_sched_barrier(0);
    }
}

// -------- final_state: bf16 h_127 -> f32 ------------------------------------
__global__ __launch_bounds__(256) void write_final(
    const short* __restrict__ Hlast, float* __restrict__ out) {
    int i = blockIdx.x * 256 + threadIdx.x;
    if (i < BATCH * HIDDEN) out[i] = bf2f(Hlast[i]);
}

extern "C" void kernel_launch(void* const* d_in, const int* in_sizes, int n_in,
                              void* d_out, int out_size, void* d_ws, size_t ws_size,
                              hipStream_t stream) {
    const int*   x   = (const int*)  d_in[0];
    const float* st  = (const float*)d_in[1];
    const float* Wxh = (const float*)d_in[2];
    const float* Whh = (const float*)d_in[3];
    const float* bh  = (const float*)d_in[4];
    const float* Who = (const float*)d_in[5];
    const float* bo  = (const float*)d_in[6];
    float* out = (float*)d_out;

    char* ws = (char*)d_ws;
    short* WhhT = (short*)ws;                                           // 2 MB
    short* WhoT = (short*)(ws + 2097152ull);                            // 65.536 MB
    short* H    = (short*)(ws + 2097152ull + 65536000ull);              // 8.389 MB
    short* S0   = (short*)(ws + 2097152ull + 65536000ull + 8388608ull); // 64 KB
    u32*   Htag = (u32*)  (ws + 2097152ull + 65536000ull + 8388608ull + 65536ull); // 256 KB

    transpose_f32_bf16<<<(1024/64)*(1024/64), 256, 0, stream>>>(Whh, WhhT, 1024, 1024);
    transpose_f32_bf16<<<(VOCAB/64)*(1024/64), 256, 0, stream>>>(Who, WhoT, 1024, VOCAB);
    f32_to_bf16_vec<<<(BATCH*HIDDEN + 255)/256, 256, 0, stream>>>(st, S0, BATCH*HIDDEN);
    hipMemsetAsync(Htag, 0, 2ull * BATCH * HIDDEN * sizeof(u32), stream);

    rnn_persistent<<<64, 256, 0, stream>>>(WhhT, Wxh, bh, x, S0, H, Htag);

    gemm_out<<<(4096/256) * (VOCAB/256), 512, 0, stream>>>(H, WhoT, bo, out);
    write_final<<<(BATCH*HIDDEN + 255)/256, 256, 0, stream>>>(
        H + (size_t)(SEQ - 1) * BATCH * HIDDEN, out + (size_t)SEQ * BATCH * VOCAB);
}

// Round 14
// 496.525 us; speedup vs baseline: 1.7326x; 1.2386x over previous
//
#include <hip/hip_runtime.h>
#include <hip/hip_bf16.h>

#define VOCAB 32000
#define HIDDEN 1024
#define BATCH 32
#define SEQ 128
#define NTILES 2000   // (4096/256) * (32000/256)

typedef short bf8v __attribute__((ext_vector_type(8)));   // 8 x bf16 payload
typedef float f32x4 __attribute__((ext_vector_type(4)));
typedef unsigned long long u64;
typedef u64 u64x2 __attribute__((ext_vector_type(2)));
typedef unsigned int u32;

static __device__ __forceinline__ short f2bf(float f) {
    return __builtin_bit_cast(short, __float2bfloat16(f));
}
static __device__ __forceinline__ float bf2f(short s) {
    unsigned u = ((unsigned)(unsigned short)s) << 16;
    return __builtin_bit_cast(float, u);
}
static __device__ __forceinline__ float fast_tanh(float v) {
    float e = __expf(2.0f * v);
    return 1.0f - 2.0f / (e + 1.0f);
}

// -------- Phase 0: transpose f32 (K rows x N cols) -> bf16 (N rows x K cols) ----
__global__ __launch_bounds__(256) void transpose_f32_bf16(
    const float* __restrict__ in, short* __restrict__ out, int K, int N) {
    __shared__ short tile[64][65];
    int ntiles = N >> 6;
    int bn = blockIdx.x % ntiles;
    int bk = blockIdx.x / ntiles;
    int tid = threadIdx.x;
#pragma unroll
    for (int i = 0; i < 16; ++i) {
        int idx = i * 256 + tid;
        int lk = idx >> 6;
        int ln = idx & 63;
        float v = __builtin_nontemporal_load(
            &in[(size_t)(bk * 64 + lk) * N + (bn * 64 + ln)]);
        tile[ln][lk] = f2bf(v);
    }
    __syncthreads();
#pragma unroll
    for (int i = 0; i < 16; ++i) {
        int idx = i * 256 + tid;
        int lnr = idx >> 6;
        int lkc = idx & 63;
        out[(size_t)(bn * 64 + lnr) * K + (bk * 64 + lkc)] = tile[lnr][lkc];
    }
}

__global__ __launch_bounds__(256) void f32_to_bf16_vec(
    const float* __restrict__ in, short* __restrict__ out, int n) {
    int i = blockIdx.x * 256 + threadIdx.x;
    if (i < n) out[i] = f2bf(in[i]);
}

// -------- Fused persistent kernel: RNN (64 blocks) + work-stealing GEMM ------
// 256 blocks x 512 thr, LDS ~153 KB => exactly 1 block/CU => all 256 resident
// (no dispatch-order assumption; rnn role assigned by atomic registration).
// RNN: r10-proven exchange (depth-2 tagged ping-pong, retry-all poll) on 512
// thr; H_t written via agent-atomic u64 stores (hst repack), acked (vmcnt 0 +
// barrier) before done[t] increment. GEMM: r10-proven 256x256 4-phase tile
// body; tiles fetched from a global counter (bm-major order) and gated on
// done[bm*8+7]==64, so A-reads (normal global_load_lds) are first-touch-after-
// MALL-visibility per XCD.
__global__ __launch_bounds__(512, 1) void rnn_gemm_fused(
    const short* __restrict__ WhhT,   // (1024 n, 1024 k) bf16
    const float* __restrict__ Wxh,    // (VOCAB, 1024) f32
    const float* __restrict__ bh,     // (1024) f32
    const int*   __restrict__ x,      // (BATCH, SEQ) int32
    const short* __restrict__ S0,     // (32,1024) bf16
    const short* __restrict__ Bw,     // WhoT (32000 n, 1024 k) bf16
    const float* __restrict__ bo,     // (32000) f32
    short* __restrict__ H,            // (SEQ, 32, 1024) bf16
    u32* __restrict__ Htag,           // (2, 32, 1024) u32 tagged ping-pong
    u32* __restrict__ done,           // [SEQ] completion counters
    u32* __restrict__ ctr,            // gemm tile counter
    u32* __restrict__ rnnctr,         // rnn registration counter
    float* __restrict__ C)            // (4096, 32000) f32
{
    __shared__ __align__(16) char lds[139264];  // gemm bufs + epi scratch
    __shared__ short hl[8 * 1024];              // rnn h rows (XOR-swizzled)
    __shared__ short hst[8 * 64];               // rnn slice repack
    __shared__ int sreg;
    __shared__ int stile;

    const int tid = threadIdx.x;
    const int lane = tid & 63;
    const int wid = tid >> 6;

    if (tid == 0)
        sreg = (int)__hip_atomic_fetch_add(rnnctr, 1u, __ATOMIC_RELAXED,
                                           __HIP_MEMORY_SCOPE_AGENT);
    __syncthreads();
    const int rb = sreg;

    if (rb < 64) {
        // ===================== RNN phase (r10 logic, 512 thr) =====================
        const int bgi = rb >> 4, cgj = rb & 15;
        const int grow0 = bgi * 8, gcol0 = cgj * 64;
        const int lrow = lane & 15, kg = lane >> 4;
        const int rx = lrow & 7;
        const bool cw = (wid < 4);                      // compute waves
        const int gcol = gcol0 + (wid & 3) * 16 + lrow;
        const float bias = cw ? bh[gcol] : 0.0f;
        const bool act = cw && (kg < 2);
        const short* aBase = hl + ((lrow & 7) << 10);

        bf8v wreg[32];
        if (cw) {
#pragma unroll
            for (int it = 0; it < 32; ++it)
                wreg[it] = *(const bf8v*)(WhhT + ((size_t)gcol << 10) + it * 32 + kg * 8);
        }
        {
            const u64* s = (const u64*)(S0 + (grow0 << 10));
#pragma unroll
            for (int j = 0; j < 4; ++j) {
                int idx = tid + 512 * j;
                int r = idx >> 8, cq = idx & 255;
                u64 v = s[idx];
                *(u64*)((char*)hl + (r << 11) + (((cq >> 1) ^ (r & 7)) << 4) + ((cq & 1) << 3)) = v;
            }
        }
        float wx[4] = {0.f, 0.f, 0.f, 0.f};
        if (act)
#pragma unroll
            for (int r = 0; r < 4; ++r) {
                int id = x[(grow0 + kg * 4 + r) * SEQ];
                wx[r] = Wxh[((size_t)id << 10) + gcol];
            }
        __syncthreads();

        for (int t = 0; t < SEQ; ++t) {
            f32x4 acc = {0.f, 0.f, 0.f, 0.f};
            if (cw) {
#pragma unroll
                for (int it = 0; it < 32; ++it) {
                    int off = ((4 * it + kg) ^ rx) << 3;
                    bf8v a = *(const bf8v*)(aBase + off);
                    acc = __builtin_amdgcn_mfma_f32_16x16x32_bf16(a, wreg[it], acc, 0, 0, 0);
                }
            }
            if (act) {
                const u32 wtag = (u32)(t + 1);
                u32* tagbuf = Htag + ((t & 1) << 15);
#pragma unroll
                for (int r = 0; r < 4; ++r) {
                    int grow = grow0 + kg * 4 + r;   // D map: col=lane&15, row=(lane>>4)*4+r
                    float v = fast_tanh(wx[r] + acc[r] + bias);
                    short bv = f2bf(v);
                    __hip_atomic_store(tagbuf + (grow << 10) + gcol,
                                       ((u32)(unsigned short)bv << 16) | wtag,
                                       __ATOMIC_RELAXED, __HIP_MEMORY_SCOPE_AGENT);
                    hst[(kg * 4 + r) * 64 + ((wid & 3) * 16 + lrow)] = bv;
                }
            }
            asm volatile("s_waitcnt lgkmcnt(0)" ::: "memory");
            __builtin_amdgcn_s_barrier();   // A': hst ready; all hl MFMA reads done

            if (tid < 128) {                // H_t slice -> MALL via atomic u64
                int row = tid >> 4, q = tid & 15;
                u64 v = *(const u64*)(hst + row * 64 + q * 4);
                u64* dst = (u64*)(H + ((size_t)t << 15) + ((size_t)(grow0 + row) << 10) + gcol0) + q;
                __hip_atomic_store(dst, v, __ATOMIC_RELAXED, __HIP_MEMORY_SCOPE_AGENT);
            }

            if (t + 1 < SEQ) {
                if (act)
#pragma unroll
                    for (int r = 0; r < 4; ++r) {
                        int id = x[(grow0 + kg * 4 + r) * SEQ + (t + 1)];
                        wx[r] = Wxh[((size_t)id << 10) + gcol];
                    }
                const u64 want = (u64)(u32)(t + 1) * 0x0000000100000001ull;
                const u64* base = (const u64*)(Htag + ((t & 1) << 15)) + (grow0 << 9);
                u64 vv[8];
#pragma unroll
                for (int j = 0; j < 8; ++j)
                    vv[j] = __hip_atomic_load(base + tid + 512 * j,
                                              __ATOMIC_RELAXED, __HIP_MEMORY_SCOPE_AGENT);
                for (;;) {
                    bool ok = true;
#pragma unroll
                    for (int j = 0; j < 8; ++j)
                        ok &= ((vv[j] & 0x0000FFFF0000FFFFull) == want);
                    if (ok) break;
#pragma unroll
                    for (int j = 0; j < 8; ++j)
                        vv[j] = __hip_atomic_load(base + tid + 512 * j,
                                                  __ATOMIC_RELAXED, __HIP_MEMORY_SCOPE_AGENT);
                }
#pragma unroll
                for (int j = 0; j < 8; ++j) {
                    int idx = tid + 512 * j;
                    int r = idx >> 9, c2 = idx & 511;
                    u32 pk = ((u32)(vv[j] >> 16) & 0xFFFFu) | ((u32)(vv[j] >> 32) & 0xFFFF0000u);
                    *(u32*)((char*)hl + (r << 11) + (((c2 >> 2) ^ (r & 7)) << 4) + ((c2 & 3) << 2)) = pk;
                }
            }
            asm volatile("s_waitcnt vmcnt(0) lgkmcnt(0)" ::: "memory");
            __builtin_amdgcn_s_barrier();   // B: hl staged; all waves' H stores acked
            if (tid == 0)
                __hip_atomic_fetch_add(done + t, 1u, __ATOMIC_RELAXED,
                                       __HIP_MEMORY_SCOPE_AGENT);
        }
    }

    // ===================== persistent GEMM phase =====================
    const int wm = wid >> 2;           // 0..1 (128-row M slice)
    const int wn = wid & 3;            // 0..3 (64-col N slice)
    const int glrow = lane & 15, gkg = lane >> 4;
    const int grx = glrow & 7;
    const int srow8 = (lane >> 3) & 7;
    const int sxor = ((lane & 7) ^ srow8) << 3;

    for (;;) {
        if (tid == 0)
            stile = (int)__hip_atomic_fetch_add(ctr, 1u, __ATOMIC_RELAXED,
                                                __HIP_MEMORY_SCOPE_AGENT);
        __syncthreads();
        const int tile = stile;
        if (tile >= NTILES) break;
        const int bm = tile / 125;         // bm-major: availability tracks rnn
        const int bn = tile - bm * 125;
        if (tid == 0) {
            while (__hip_atomic_load(done + (bm * 8 + 7), __ATOMIC_RELAXED,
                                     __HIP_MEMORY_SCOPE_AGENT) < 64u)
                __builtin_amdgcn_s_sleep(2);
        }
        __syncthreads();                   // gate passed; also protects LDS reuse

        const size_t a0 = (size_t)bm * 256;
        const size_t b0 = (size_t)bn * 256;
        f32x4 acc[8][4] = {};

#define STAGEH(TT, HH)                                                        \
    {                                                                         \
        const short* gs_ = ((HH) < 2) ? H : Bw;                               \
        const size_t rb_ = (((HH) < 2) ? a0 : b0) + (size_t)((HH) & 1) * 128; \
        char* db_ = lds + (((HH) < 2) ? 0 : 65536) + ((TT) & 1) * 32768       \
                    + ((HH) & 1) * 16384 + wid * 1024;                        \
        const int kk_ = (TT) * 64;                                            \
        _Pragma("unroll")                                                     \
        for (int c_ = 0; c_ < 2; ++c_) {                                      \
            const short* src_ = gs_ + (rb_ + c_ * 64 + wid * 8 + srow8) * 1024\
                                + kk_ + sxor;                                 \
            __builtin_amdgcn_global_load_lds(                                 \
                (const __attribute__((address_space(1))) void*)src_,          \
                (__attribute__((address_space(3))) void*)(db_ + c_ * 8192),   \
                16, 0, 0);                                                    \
        }                                                                     \
    }

        STAGEH(0, 0); STAGEH(0, 1); STAGEH(0, 2); STAGEH(0, 3);

#pragma unroll 1
        for (int t = 0; t < 16; ++t) {
            __builtin_amdgcn_sched_barrier(0);
            __builtin_amdgcn_s_barrier();        // all waves done reading tile t-1
            __builtin_amdgcn_sched_barrier(0);
            if (t + 1 < 16) {
                STAGEH(t + 1, 0); STAGEH(t + 1, 1); STAGEH(t + 1, 2);
                asm volatile("s_waitcnt vmcnt(6)" ::: "memory");
            } else {
                asm volatile("s_waitcnt vmcnt(0)" ::: "memory");
            }
            __builtin_amdgcn_sched_barrier(0);
            __builtin_amdgcn_s_barrier();        // tile t visible to all
            __builtin_amdgcn_sched_barrier(0);

            const char* Ab = lds + (t & 1) * 32768;
            const char* Bb = lds + 65536 + (t & 1) * 32768;

            bf8v bfr[4][2];
#pragma unroll
            for (int nj = 0; nj < 4; ++nj)
#pragma unroll
                for (int ks = 0; ks < 2; ++ks)
                    bfr[nj][ks] = *(const bf8v*)(Bb + (wn * 64 + nj * 16 + glrow) * 128
                                                 + ((((ks << 2) + gkg) ^ grx) << 4));

#pragma unroll
            for (int q = 0; q < 4; ++q) {
                if (q == 1 && t + 1 < 16) STAGEH(t + 1, 3);
                bf8v af[2][2];
#pragma unroll
                for (int i = 0; i < 2; ++i)
#pragma unroll
                    for (int ks = 0; ks < 2; ++ks)
                        af[i][ks] = *(const bf8v*)(Ab
                            + (wm * 128 + (q * 2 + i) * 16 + glrow) * 128
                            + ((((ks << 2) + gkg) ^ grx) << 4));
                __builtin_amdgcn_sched_barrier(0);
                __builtin_amdgcn_s_setprio(1);
#pragma unroll
                for (int ks = 0; ks < 2; ++ks)
#pragma unroll
                    for (int i = 0; i < 2; ++i)
#pragma unroll
                        for (int nj = 0; nj < 4; ++nj)
                            acc[q * 2 + i][nj] = __builtin_amdgcn_mfma_f32_16x16x32_bf16(
                                af[i][ks], bfr[nj][ks], acc[q * 2 + i][nj], 0, 0, 0);
                __builtin_amdgcn_s_setprio(0);
                __builtin_amdgcn_sched_barrier(0);
            }
        }
#undef STAGEH

        __builtin_amdgcn_sched_barrier(0);
        __builtin_amdgcn_s_barrier();            // all LDS buffer reads complete
        char* wbase = lds + wid * 17408;         // 64 rows x 272 B per wave
#pragma unroll
        for (int half = 0; half < 2; ++half) {
#pragma unroll
            for (int nj = 0; nj < 4; ++nj) {
                float bias = bo[b0 + wn * 64 + nj * 16 + glrow];
#pragma unroll
                for (int mi2 = 0; mi2 < 4; ++mi2)
#pragma unroll
                    for (int r = 0; r < 4; ++r)
                        *(float*)(wbase + (mi2 * 16 + gkg * 4 + r) * 272
                                  + (nj * 16 + glrow) * 4)
                            = acc[half * 4 + mi2][nj][r] + bias;
            }
            asm volatile("s_waitcnt lgkmcnt(0)" ::: "memory");
            __builtin_amdgcn_sched_barrier(0);
#pragma unroll
            for (int p = 0; p < 16; ++p) {
                int lr = p * 4 + (lane >> 4);
                f32x4 v = *(const f32x4*)(wbase + lr * 272 + (lane & 15) * 16);
                size_t row_g = a0 + wm * 128 + half * 64 + lr;
                int col_g = (int)b0 + wn * 64 + (lane & 15) * 4;
                __builtin_nontemporal_store(v, (f32x4*)&C[row_g * VOCAB + col_g]);
            }
            asm volatile("s_waitcnt lgkmcnt(0)" ::: "memory");
            __builtin_amdgcn_sched_barrier(0);
        }
    }
}

// -------- final_state: bf16 h_127 -> f32 ------------------------------------
__global__ __launch_bounds__(256) void write_final(
    const short* __restrict__ Hlast, float* __restrict__ out) {
    int i = blockIdx.x * 256 + threadIdx.x;
    if (i < BATCH * HIDDEN) out[i] = bf2f(Hlast[i]);
}

extern "C" void kernel_launch(void* const* d_in, const int* in_sizes, int n_in,
                              void* d_out, int out_size, void* d_ws, size_t ws_size,
                              hipStream_t stream) {
    const int*   x   = (const int*)  d_in[0];
    const float* st  = (const float*)d_in[1];
    const float* Wxh = (const float*)d_in[2];
    const float* Whh = (const float*)d_in[3];
    const float* bh  = (const float*)d_in[4];
    const float* Who = (const float*)d_in[5];
    const float* bo  = (const float*)d_in[6];
    float* out = (float*)d_out;

    char* ws = (char*)d_ws;
    short* WhhT = (short*)ws;                                           // 2 MB
    short* WhoT = (short*)(ws + 2097152ull);                            // 65.536 MB
    short* H    = (short*)(ws + 2097152ull + 65536000ull);              // 8.389 MB
    short* S0   = (short*)(ws + 2097152ull + 65536000ull + 8388608ull); // 64 KB
    u32*   Htag = (u32*)  (ws + 2097152ull + 65536000ull + 8388608ull + 65536ull); // 256 KB
    u32*   done = Htag + 65536;          // 128 u32
    u32*   ctr  = done + 128;            // 1 u32
    u32*   rnnc = ctr + 1;               // 1 u32

    transpose_f32_bf16<<<(1024/64)*(1024/64), 256, 0, stream>>>(Whh, WhhT, 1024, 1024);
    transpose_f32_bf16<<<(VOCAB/64)*(1024/64), 256, 0, stream>>>(Who, WhoT, 1024, VOCAB);
    f32_to_bf16_vec<<<(BATCH*HIDDEN + 255)/256, 256, 0, stream>>>(st, S0, BATCH*HIDDEN);
    hipMemsetAsync(Htag, 0, 262144ull + 512ull + 8ull, stream);

    rnn_gemm_fused<<<256, 512, 0, stream>>>(WhhT, Wxh, bh, x, S0, WhoT, bo,
                                            H, Htag, done, ctr, rnnc, out);

    write_final<<<(BATCH*HIDDEN + 255)/256, 256, 0, stream>>>(
        H + (size_t)(SEQ - 1) * BATCH * HIDDEN, out + (size_t)SEQ * BATCH * VOCAB);
}

// Round 15
// 471.526 us; speedup vs baseline: 1.8244x; 1.0530x over previous
//
#include <hip/hip_runtime.h>
#include <hip/hip_bf16.h>

#define VOCAB 32000
#define HIDDEN 1024
#define BATCH 32
#define SEQ 128
#define NTILES 2000   // (4096/256) * (32000/256)
#define RNNB 32       // rnn team size (8 col-groups x 4 row-groups)

typedef short bf8v __attribute__((ext_vector_type(8)));   // 8 x bf16 payload
typedef float f32x4 __attribute__((ext_vector_type(4)));
typedef unsigned long long u64;
typedef unsigned int u32;

static __device__ __forceinline__ short f2bf(float f) {
    return __builtin_bit_cast(short, __float2bfloat16(f));
}
static __device__ __forceinline__ float bf2f(short s) {
    unsigned u = ((unsigned)(unsigned short)s) << 16;
    return __builtin_bit_cast(float, u);
}
static __device__ __forceinline__ float fast_tanh(float v) {
    float e = __expf(2.0f * v);
    return 1.0f - 2.0f / (e + 1.0f);
}

// -------- Phase 0: transpose f32 (K rows x N cols) -> bf16 (N rows x K cols) ----
__global__ __launch_bounds__(256) void transpose_f32_bf16(
    const float* __restrict__ in, short* __restrict__ out, int K, int N) {
    __shared__ short tile[64][65];
    int ntiles = N >> 6;
    int bn = blockIdx.x % ntiles;
    int bk = blockIdx.x / ntiles;
    int tid = threadIdx.x;
#pragma unroll
    for (int i = 0; i < 16; ++i) {
        int idx = i * 256 + tid;
        int lk = idx >> 6;
        int ln = idx & 63;
        float v = __builtin_nontemporal_load(
            &in[(size_t)(bk * 64 + lk) * N + (bn * 64 + ln)]);
        tile[ln][lk] = f2bf(v);
    }
    __syncthreads();
#pragma unroll
    for (int i = 0; i < 16; ++i) {
        int idx = i * 256 + tid;
        int lnr = idx >> 6;
        int lkc = idx & 63;
        out[(size_t)(bn * 64 + lnr) * K + (bk * 64 + lkc)] = tile[lnr][lkc];
    }
}

__global__ __launch_bounds__(256) void f32_to_bf16_vec(
    const float* __restrict__ in, short* __restrict__ out, int n) {
    int i = blockIdx.x * 256 + threadIdx.x;
    if (i < n) out[i] = f2bf(in[i]);
}

// -------- Fused persistent kernel: RNN (32 blocks) + work-stealing GEMM ------
// 256 blocks x 512 thr, 1 block/CU, all resident. RNN team shrunk 64->32
// (each block: 8 rows x 128 cols, all 8 waves compute) so 224 CUs do gemm
// during the recurrence: capacity 7.0 tiles/us > availability 5.8 tiles/us
// (the r14 64-block split was a 6.0-vs-5.8 knife edge -> queueing backlog).
// Exchange protocol and poll code byte-identical to the r10-proven version.
__global__ __launch_bounds__(512, 1) void rnn_gemm_fused(
    const short* __restrict__ WhhT,   // (1024 n, 1024 k) bf16
    const float* __restrict__ Wxh,    // (VOCAB, 1024) f32
    const float* __restrict__ bh,     // (1024) f32
    const int*   __restrict__ x,      // (BATCH, SEQ) int32
    const short* __restrict__ S0,     // (32,1024) bf16
    const short* __restrict__ Bw,     // WhoT (32000 n, 1024 k) bf16
    const float* __restrict__ bo,     // (32000) f32
    short* __restrict__ H,            // (SEQ, 32, 1024) bf16
    u32* __restrict__ Htag,           // (2, 32, 1024) u32 tagged ping-pong
    u32* __restrict__ done,           // [SEQ] completion counters
    u32* __restrict__ ctr,            // gemm tile counter
    u32* __restrict__ rnnctr,         // rnn registration counter
    float* __restrict__ C)            // (4096, 32000) f32
{
    __shared__ __align__(16) char lds[139264];  // gemm bufs + epi scratch
    __shared__ short hl[8 * 1024];              // rnn h rows (XOR-swizzled)
    __shared__ short hst[8 * 128];              // rnn slice repack
    __shared__ int sreg;
    __shared__ int stile;

    const int tid = threadIdx.x;
    const int lane = tid & 63;
    const int wid = tid >> 6;

    if (tid == 0)
        sreg = (int)__hip_atomic_fetch_add(rnnctr, 1u, __ATOMIC_RELAXED,
                                           __HIP_MEMORY_SCOPE_AGENT);
    __syncthreads();
    const int rb = sreg;

    if (rb < RNNB) {
        // ===================== RNN phase (8 waves, 128 cols/block) ==============
        const int bgi = rb >> 3, cgj8 = rb & 7;
        const int grow0 = bgi * 8, gcol0 = cgj8 * 128;
        const int lrow = lane & 15, kg = lane >> 4;
        const int rx = lrow & 7;
        const int gcol = gcol0 + wid * 16 + lrow;   // h column this lane produces
        const float bias = bh[gcol];
        const bool act = (kg < 2);
        const short* aBase = hl + ((lrow & 7) << 10);

        bf8v wreg[32];
#pragma unroll
        for (int it = 0; it < 32; ++it)
            wreg[it] = *(const bf8v*)(WhhT + ((size_t)gcol << 10) + it * 32 + kg * 8);

        {
            const u64* s = (const u64*)(S0 + (grow0 << 10));
#pragma unroll
            for (int j = 0; j < 4; ++j) {
                int idx = tid + 512 * j;
                int r = idx >> 8, cq = idx & 255;
                u64 v = s[idx];
                *(u64*)((char*)hl + (r << 11) + (((cq >> 1) ^ (r & 7)) << 4) + ((cq & 1) << 3)) = v;
            }
        }
        float wx[4] = {0.f, 0.f, 0.f, 0.f};
        if (act)
#pragma unroll
            for (int r = 0; r < 4; ++r) {
                int id = x[(grow0 + kg * 4 + r) * SEQ];
                wx[r] = Wxh[((size_t)id << 10) + gcol];
            }
        __syncthreads();

        for (int t = 0; t < SEQ; ++t) {
            f32x4 acc = {0.f, 0.f, 0.f, 0.f};
#pragma unroll
            for (int it = 0; it < 32; ++it) {
                int off = ((4 * it + kg) ^ rx) << 3;
                bf8v a = *(const bf8v*)(aBase + off);
                acc = __builtin_amdgcn_mfma_f32_16x16x32_bf16(a, wreg[it], acc, 0, 0, 0);
            }
            if (act) {
                const u32 wtag = (u32)(t + 1);
                u32* tagbuf = Htag + ((t & 1) << 15);
#pragma unroll
                for (int r = 0; r < 4; ++r) {
                    int grow = grow0 + kg * 4 + r;   // D map: col=lane&15, row=(lane>>4)*4+r
                    float v = fast_tanh(wx[r] + acc[r] + bias);
                    short bv = f2bf(v);
                    __hip_atomic_store(tagbuf + (grow << 10) + gcol,
                                       ((u32)(unsigned short)bv << 16) | wtag,
                                       __ATOMIC_RELAXED, __HIP_MEMORY_SCOPE_AGENT);
                    hst[(kg * 4 + r) * 128 + (wid * 16 + lrow)] = bv;
                }
            }
            asm volatile("s_waitcnt lgkmcnt(0)" ::: "memory");
            __builtin_amdgcn_s_barrier();   // hst ready; all hl MFMA reads done

            if (tid < 256) {                // H_t slice -> MALL via atomic u64
                int row = tid >> 5, q = tid & 31;
                u64 v = *(const u64*)(hst + row * 128 + q * 4);
                u64* dst = (u64*)(H + ((size_t)t << 15) + ((size_t)(grow0 + row) << 10) + gcol0) + q;
                __hip_atomic_store(dst, v, __ATOMIC_RELAXED, __HIP_MEMORY_SCOPE_AGENT);
            }

            if (t + 1 < SEQ) {
                if (act)
#pragma unroll
                    for (int r = 0; r < 4; ++r) {
                        int id = x[(grow0 + kg * 4 + r) * SEQ + (t + 1)];
                        wx[r] = Wxh[((size_t)id << 10) + gcol];
                    }
                const u64 want = (u64)(u32)(t + 1) * 0x0000000100000001ull;
                const u64* base = (const u64*)(Htag + ((t & 1) << 15)) + (grow0 << 9);
                u64 vv[8];
#pragma unroll
                for (int j = 0; j < 8; ++j)
                    vv[j] = __hip_atomic_load(base + tid + 512 * j,
                                              __ATOMIC_RELAXED, __HIP_MEMORY_SCOPE_AGENT);
                for (;;) {
                    bool ok = true;
#pragma unroll
                    for (int j = 0; j < 8; ++j)
                        ok &= ((vv[j] & 0x0000FFFF0000FFFFull) == want);
                    if (ok) break;
#pragma unroll
                    for (int j = 0; j < 8; ++j)
                        vv[j] = __hip_atomic_load(base + tid + 512 * j,
                                                  __ATOMIC_RELAXED, __HIP_MEMORY_SCOPE_AGENT);
                }
#pragma unroll
                for (int j = 0; j < 8; ++j) {
                    int idx = tid + 512 * j;
                    int r = idx >> 9, c2 = idx & 511;
                    u32 pk = ((u32)(vv[j] >> 16) & 0xFFFFu) | ((u32)(vv[j] >> 32) & 0xFFFF0000u);
                    *(u32*)((char*)hl + (r << 11) + (((c2 >> 2) ^ (r & 7)) << 4) + ((c2 & 3) << 2)) = pk;
                }
            }
            asm volatile("s_waitcnt vmcnt(0) lgkmcnt(0)" ::: "memory");
            __builtin_amdgcn_s_barrier();   // hl staged; all H stores acked
            if (tid == 0)
                __hip_atomic_fetch_add(done + t, 1u, __ATOMIC_RELAXED,
                                       __HIP_MEMORY_SCOPE_AGENT);
        }
    }

    // ===================== persistent GEMM phase =====================
    const int wm = wid >> 2;           // 0..1 (128-row M slice)
    const int wn = wid & 3;            // 0..3 (64-col N slice)
    const int glrow = lane & 15, gkg = lane >> 4;
    const int grx = glrow & 7;
    const int srow8 = (lane >> 3) & 7;
    const int sxor = ((lane & 7) ^ srow8) << 3;

    for (;;) {
        if (tid == 0)
            stile = (int)__hip_atomic_fetch_add(ctr, 1u, __ATOMIC_RELAXED,
                                                __HIP_MEMORY_SCOPE_AGENT);
        __syncthreads();
        const int tile = stile;
        if (tile >= NTILES) break;
        const int bm = tile / 125;         // bm-major: availability tracks rnn
        const int bn = tile - bm * 125;
        if (tid == 0) {
            while (__hip_atomic_load(done + (bm * 8 + 7), __ATOMIC_RELAXED,
                                     __HIP_MEMORY_SCOPE_AGENT) < (u32)RNNB)
                __builtin_amdgcn_s_sleep(2);
        }
        __syncthreads();                   // gate passed; also protects LDS reuse

        const size_t a0 = (size_t)bm * 256;
        const size_t b0 = (size_t)bn * 256;
        f32x4 acc[8][4] = {};

#define STAGEH(TT, HH)                                                        \
    {                                                                         \
        const short* gs_ = ((HH) < 2) ? H : Bw;                               \
        const size_t rb_ = (((HH) < 2) ? a0 : b0) + (size_t)((HH) & 1) * 128; \
        char* db_ = lds + (((HH) < 2) ? 0 : 65536) + ((TT) & 1) * 32768       \
                    + ((HH) & 1) * 16384 + wid * 1024;                        \
        const int kk_ = (TT) * 64;                                            \
        _Pragma("unroll")                                                     \
        for (int c_ = 0; c_ < 2; ++c_) {                                      \
            const short* src_ = gs_ + (rb_ + c_ * 64 + wid * 8 + srow8) * 1024\
                                + kk_ + sxor;                                 \
            __builtin_amdgcn_global_load_lds(                                 \
                (const __attribute__((address_space(1))) void*)src_,          \
                (__attribute__((address_space(3))) void*)(db_ + c_ * 8192),   \
                16, 0, 0);                                                    \
        }                                                                     \
    }

        STAGEH(0, 0); STAGEH(0, 1); STAGEH(0, 2); STAGEH(0, 3);

#pragma unroll 1
        for (int t = 0; t < 16; ++t) {
            __builtin_amdgcn_sched_barrier(0);
            __builtin_amdgcn_s_barrier();        // all waves done reading tile t-1
            __builtin_amdgcn_sched_barrier(0);
            if (t + 1 < 16) {
                STAGEH(t + 1, 0); STAGEH(t + 1, 1); STAGEH(t + 1, 2);
                asm volatile("s_waitcnt vmcnt(6)" ::: "memory");
            } else {
                asm volatile("s_waitcnt vmcnt(0)" ::: "memory");
            }
            __builtin_amdgcn_sched_barrier(0);
            __builtin_amdgcn_s_barrier();        // tile t visible to all
            __builtin_amdgcn_sched_barrier(0);

            const char* Ab = lds + (t & 1) * 32768;
            const char* Bb = lds + 65536 + (t & 1) * 32768;

            bf8v bfr[4][2];
#pragma unroll
            for (int nj = 0; nj < 4; ++nj)
#pragma unroll
                for (int ks = 0; ks < 2; ++ks)
                    bfr[nj][ks] = *(const bf8v*)(Bb + (wn * 64 + nj * 16 + glrow) * 128
                                                 + ((((ks << 2) + gkg) ^ grx) << 4));

#pragma unroll
            for (int q = 0; q < 4; ++q) {
                if (q == 1 && t + 1 < 16) STAGEH(t + 1, 3);
                bf8v af[2][2];
#pragma unroll
                for (int i = 0; i < 2; ++i)
#pragma unroll
                    for (int ks = 0; ks < 2; ++ks)
                        af[i][ks] = *(const bf8v*)(Ab
                            + (wm * 128 + (q * 2 + i) * 16 + glrow) * 128
                            + ((((ks << 2) + gkg) ^ grx) << 4));
                __builtin_amdgcn_sched_barrier(0);
                __builtin_amdgcn_s_setprio(1);
#pragma unroll
                for (int ks = 0; ks < 2; ++ks)
#pragma unroll
                    for (int i = 0; i < 2; ++i)
#pragma unroll
                        for (int nj = 0; nj < 4; ++nj)
                            acc[q * 2 + i][nj] = __builtin_amdgcn_mfma_f32_16x16x32_bf16(
                                af[i][ks], bfr[nj][ks], acc[q * 2 + i][nj], 0, 0, 0);
                __builtin_amdgcn_s_setprio(0);
                __builtin_amdgcn_sched_barrier(0);
            }
        }
#undef STAGEH

        __builtin_amdgcn_sched_barrier(0);
        __builtin_amdgcn_s_barrier();            // all LDS buffer reads complete
        char* wbase = lds + wid * 17408;         // 64 rows x 272 B per wave
#pragma unroll
        for (int half = 0; half < 2; ++half) {
#pragma unroll
            for (int nj = 0; nj < 4; ++nj) {
                float bias = bo[b0 + wn * 64 + nj * 16 + glrow];
#pragma unroll
                for (int mi2 = 0; mi2 < 4; ++mi2)
#pragma unroll
                    for (int r = 0; r < 4; ++r)
                        *(float*)(wbase + (mi2 * 16 + gkg * 4 + r) * 272
                                  + (nj * 16 + glrow) * 4)
                            = acc[half * 4 + mi2][nj][r] + bias;
            }
            asm volatile("s_waitcnt lgkmcnt(0)" ::: "memory");
            __builtin_amdgcn_sched_barrier(0);
#pragma unroll
            for (int p = 0; p < 16; ++p) {
                int lr = p * 4 + (lane >> 4);
                f32x4 v = *(const f32x4*)(wbase + lr * 272 + (lane & 15) * 16);
                size_t row_g = a0 + wm * 128 + half * 64 + lr;
                int col_g = (int)b0 + wn * 64 + (lane & 15) * 4;
                __builtin_nontemporal_store(v, (f32x4*)&C[row_g * VOCAB + col_g]);
            }
            asm volatile("s_waitcnt lgkmcnt(0)" ::: "memory");
            __builtin_amdgcn_sched_barrier(0);
        }
    }
}

// -------- final_state: bf16 h_127 -> f32 ------------------------------------
__global__ __launch_bounds__(256) void write_final(
    const short* __restrict__ Hlast, float* __restrict__ out) {
    int i = blockIdx.x * 256 + threadIdx.x;
    if (i < BATCH * HIDDEN) out[i] = bf2f(Hlast[i]);
}

extern "C" void kernel_launch(void* const* d_in, const int* in_sizes, int n_in,
                              void* d_out, int out_size, void* d_ws, size_t ws_size,
                              hipStream_t stream) {
    const int*   x   = (const int*)  d_in[0];
    const float* st  = (const float*)d_in[1];
    const float* Wxh = (const float*)d_in[2];
    const float* Whh = (const float*)d_in[3];
    const float* bh  = (const float*)d_in[4];
    const float* Who = (const float*)d_in[5];
    const float* bo  = (const float*)d_in[6];
    float* out = (float*)d_out;

    char* ws = (char*)d_ws;
    short* WhhT = (short*)ws;                                           // 2 MB
    short* WhoT = (short*)(ws + 2097152ull);                            // 65.536 MB
    short* H    = (short*)(ws + 2097152ull + 65536000ull);              // 8.389 MB
    short* S0   = (short*)(ws + 2097152ull + 65536000ull + 8388608ull); // 64 KB
    u32*   Htag = (u32*)  (ws + 2097152ull + 65536000ull + 8388608ull + 65536ull); // 256 KB
    u32*   done = Htag + 65536;          // 128 u32
    u32*   ctr  = done + 128;            // 1 u32
    u32*   rnnc = ctr + 1;               // 1 u32

    transpose_f32_bf16<<<(1024/64)*(1024/64), 256, 0, stream>>>(Whh, WhhT, 1024, 1024);
    transpose_f32_bf16<<<(VOCAB/64)*(1024/64), 256, 0, stream>>>(Who, WhoT, 1024, VOCAB);
    f32_to_bf16_vec<<<(BATCH*HIDDEN + 255)/256, 256, 0, stream>>>(st, S0, BATCH*HIDDEN);
    hipMemsetAsync(Htag, 0, 262144ull + 512ull + 8ull, stream);

    rnn_gemm_fused<<<256, 512, 0, stream>>>(WhhT, Wxh, bh, x, S0, WhoT, bo,
                                            H, Htag, done, ctr, rnnc, out);

    write_final<<<(BATCH*HIDDEN + 255)/256, 256, 0, stream>>>(
        H + (size_t)(SEQ - 1) * BATCH * HIDDEN, out + (size_t)SEQ * BATCH * VOCAB);
}